// Round 5
// baseline (153.935 us; speedup 1.0000x reference)
//
#include <hip/hip_runtime.h>

#define B_  16
#define LQ  256
#define LK  256
#define QD  256
#define HD  128
#define VD  128

// 2*log2(e): exp2(SCALE2*x) = e^{2x}
#define SCALE2 2.8853900817779268f
#define L2E    1.4426950408889634f
#define CTX_SIZE (B_ * LK * VD)

__device__ __forceinline__ float fast_exp2(float x) { return __builtin_amdgcn_exp2f(x); }
__device__ __forceinline__ float fast_rcp(float x)  { return __builtin_amdgcn_rcpf(x); }

// ---------------------------------------------------------------------------
// proj_kernel: 1024 blocks x 256 threads, XCD-affine: batch b -> XCD (b&7).
//   qe4[b][h4][q] = exp2(SCALE2*(query@Wq)) (float4 over 4 h, q-contig)
//   ke4[b][k][h4] = exp2(SCALE2*(key@Wk))   (row-major float4)
// ---------------------------------------------------------------------------
__global__ __launch_bounds__(256, 4) void proj_kernel(const float* __restrict__ query,
                                                      const float* __restrict__ key,
                                                      const float* __restrict__ Wq,
                                                      const float* __restrict__ Wk,
                                                      float4* __restrict__ qe4,
                                                      float4* __restrict__ ke4)
{
    __shared__ float  Xs[8][258];
    __shared__ float4 part[4][32][9];

    const int t = threadIdx.x;
    // XCD-affine decode: blockIdx%8 selects XCD; all blocks for batch b land on XCD b&7.
    const int xcd = blockIdx.x & 7;
    const int i   = blockIdx.x >> 3;         // 0..127
    const bool isQ = (i < 64);
    const int j    = isQ ? i : (i - 64);     // 0..63
    const int b    = xcd + ((j >> 5) << 3);  // {xcd, xcd+8}
    const int rows0 = b * 256 + (j & 31) * 8;

    const float* X = isQ ? query : key;
    const float4* W4 = (const float4*)(isQ ? Wq : Wk);

    {
        const int r = t >> 5;
        const int c = (t & 31) * 8;
        const float4 x0 = *(const float4*)(X + (size_t)(rows0 + r) * QD + c);
        const float4 x1 = *(const float4*)(X + (size_t)(rows0 + r) * QD + c + 4);
        *(float4*)&Xs[r][c]     = x0;
        *(float4*)&Xs[r][c + 4] = x1;
    }
    __syncthreads();

    const int w    = t >> 6;
    const int lane = t & 63;
    const int hg   = lane & 31;
    const int mb   = lane >> 5;

    float4 acc[4];
#pragma unroll
    for (int m = 0; m < 4; m++) acc[m] = make_float4(0.f, 0.f, 0.f, 0.f);

    const int kbase = w * 64;
#pragma unroll 4
    for (int kk = 0; kk < 64; kk += 2) {
        const int k = kbase + kk;
        const float4 w0 = W4[(size_t)k * 32 + hg];
        const float4 w1 = W4[(size_t)(k + 1) * 32 + hg];
#pragma unroll
        for (int mi = 0; mi < 4; mi++) {
            const float2 x = *(const float2*)&Xs[mb + 2 * mi][k];
            acc[mi].x += x.x * w0.x + x.y * w1.x;
            acc[mi].y += x.x * w0.y + x.y * w1.y;
            acc[mi].z += x.x * w0.z + x.y * w1.z;
            acc[mi].w += x.x * w0.w + x.y * w1.w;
        }
    }
#pragma unroll
    for (int mi = 0; mi < 4; mi++) part[w][hg][mb + 2 * mi] = acc[mi];
    __syncthreads();

    if (isQ) {
        const int q8 = t & 7, h4 = t >> 3;
        float4 s = part[0][h4][q8];
        const float4 p1 = part[1][h4][q8];
        const float4 p2 = part[2][h4][q8];
        const float4 p3 = part[3][h4][q8];
        s.x += p1.x + p2.x + p3.x;  s.y += p1.y + p2.y + p3.y;
        s.z += p1.z + p2.z + p3.z;  s.w += p1.w + p2.w + p3.w;
        const float4 e = make_float4(fast_exp2(s.x * SCALE2), fast_exp2(s.y * SCALE2),
                                     fast_exp2(s.z * SCALE2), fast_exp2(s.w * SCALE2));
        const int row = rows0 + q8, bb = row >> 8, q = row & 255;
        qe4[((size_t)bb * 32 + h4) * 256 + q] = e;
    } else {
        const int h4 = t & 31, m = t >> 5;
        float4 s = part[0][h4][m];
        const float4 p1 = part[1][h4][m];
        const float4 p2 = part[2][h4][m];
        const float4 p3 = part[3][h4][m];
        s.x += p1.x + p2.x + p3.x;  s.y += p1.y + p2.y + p3.y;
        s.z += p1.z + p2.z + p3.z;  s.w += p1.w + p2.w + p3.w;
        const float4 e = make_float4(fast_exp2(s.x * SCALE2), fast_exp2(s.y * SCALE2),
                                     fast_exp2(s.z * SCALE2), fast_exp2(s.w * SCALE2));
        ke4[(size_t)(rows0 + m) * 32 + h4] = e;
    }
}

// ---------------------------------------------------------------------------
// attn_kernel: 512 blocks x 1024 threads, XCD-affine (batch b -> XCD b&7).
// Block = (b, 8 k). Phase 1: thread=(q, kq) -> 2 k, 8 qe loads in flight.
// Phase 2: waves 0-7 softmax over q for k=w.
// Phase 3: value staged in LDS chunks (32 q rows), pure LDS+FMA inner loop.
// ---------------------------------------------------------------------------
__global__ __launch_bounds__(1024, 8) void attn_kernel(const float4* __restrict__ qe4,
                                                       const float4* __restrict__ ke4,
                                                       const float* __restrict__ v,
                                                       const float* __restrict__ value,
                                                       float* __restrict__ out)
{
    __shared__ float  score_s[8][260];
    __shared__ float  attn_T[256][9];
    __shared__ float  Vs[32][130];
    __shared__ float2 partc[2][8][64];

    const int t   = threadIdx.x;
    const int xcd = blockIdx.x & 7;
    const int i   = blockIdx.x >> 3;        // 0..63
    const int b   = xcd + ((i >> 5) << 3);  // {xcd, xcd+8}
    const int k0  = (i & 31) << 3;

    const int kq = t >> 8;                  // 0..3 (wave-uniform)
    const int q  = t & 255;

    const float4* qb = qe4 + (size_t)b * 32 * 256;                 // [h4][q]
    const float4* kb = ke4 + ((size_t)b * LK + k0 + kq * 2) * 32;  // 2 rows
    const float4* v4 = (const float4*)v;

    // ---- Phase 1: 8 qe loads batched per group for MLP ----
    float acc0 = 0.f, acc1 = 0.f;
#pragma unroll
    for (int g = 0; g < 4; g++) {
        float4 qv[8];
#pragma unroll
        for (int jj = 0; jj < 8; jj++) qv[jj] = qb[(size_t)(g * 8 + jj) * 256 + q];
#pragma unroll
        for (int jj = 0; jj < 8; jj++) {
            const int h4 = g * 8 + jj;
            const float4 vv = v4[h4];
            const float4 ka = kb[h4];
            const float4 kc = kb[32 + h4];
            acc0 += vv.x * fast_rcp(qv[jj].x * ka.x + 1.f) + vv.y * fast_rcp(qv[jj].y * ka.y + 1.f)
                  + vv.z * fast_rcp(qv[jj].z * ka.z + 1.f) + vv.w * fast_rcp(qv[jj].w * ka.w + 1.f);
            acc1 += vv.x * fast_rcp(qv[jj].x * kc.x + 1.f) + vv.y * fast_rcp(qv[jj].y * kc.y + 1.f)
                  + vv.z * fast_rcp(qv[jj].z * kc.z + 1.f) + vv.w * fast_rcp(qv[jj].w * kc.w + 1.f);
        }
    }
    float sumv = 0.f;  // wave-uniform
#pragma unroll
    for (int h4 = 0; h4 < 32; h4++) {
        const float4 vv = v4[h4];
        sumv += vv.x + vv.y + vv.z + vv.w;
    }
    score_s[kq * 2 + 0][q] = sumv - 2.f * acc0;
    score_s[kq * 2 + 1][q] = sumv - 2.f * acc1;
    __syncthreads();

    // ---- Phase 2: softmax over q; waves 0-7 handle k = w ----
    if (t < 512) {
        const int w = t >> 6, lane = t & 63;
        float x0 = score_s[w][lane];
        float x1 = score_s[w][lane + 64];
        float x2 = score_s[w][lane + 128];
        float x3 = score_s[w][lane + 192];
        float m = fmaxf(fmaxf(x0, x1), fmaxf(x2, x3));
#pragma unroll
        for (int off = 32; off >= 1; off >>= 1) m = fmaxf(m, __shfl_xor(m, off));
        float e0 = fast_exp2((x0 - m) * L2E);
        float e1 = fast_exp2((x1 - m) * L2E);
        float e2 = fast_exp2((x2 - m) * L2E);
        float e3 = fast_exp2((x3 - m) * L2E);
        float s = e0 + e1 + e2 + e3;
#pragma unroll
        for (int off = 32; off >= 1; off >>= 1) s += __shfl_xor(s, off);
        const float rs = fast_rcp(s);
        e0 *= rs; e1 *= rs; e2 *= rs; e3 *= rs;
        attn_T[lane][w]       = e0;
        attn_T[lane + 64][w]  = e1;
        attn_T[lane + 128][w] = e2;
        attn_T[lane + 192][w] = e3;
        float* ao = out + CTX_SIZE + ((size_t)(b * LK + k0 + w)) * LQ;
        ao[lane]       = e0;
        ao[lane + 64]  = e1;
        ao[lane + 128] = e2;
        ao[lane + 192] = e3;
    }

    // ---- Phase 3: context via LDS-staged value chunks ----
    const int w = t >> 6, lane = t & 63;
    const int k = w & 7, half = w >> 3;
    const float* valb = value + (size_t)b * LQ * VD;
    float2 c = {0.f, 0.f};
    for (int ch = 0; ch < 8; ch++) {
        __syncthreads();   // previous chunk consumed (and, on ch=0, phase-2 done)
#pragma unroll
        for (int sub = 0; sub < 2; sub++) {
            const int r = sub * 16 + (t >> 6);              // 0..31
            const float2 vv = *(const float2*)(valb + (size_t)(ch * 32 + r) * VD + (t & 63) * 2);
            *(float2*)&Vs[r][(t & 63) * 2] = vv;
        }
        __syncthreads();
        const int qbase = half * 16;
#pragma unroll 4
        for (int iq = 0; iq < 16; iq++) {
            const int qr = qbase + iq;
            const float a = attn_T[ch * 32 + qr][k];        // broadcast
            const float2 vv = *(const float2*)&Vs[qr][lane * 2];
            c.x += a * vv.x;
            c.y += a * vv.y;
        }
    }
    partc[half][k][lane] = c;
    __syncthreads();
    if (t < 512) {
        const int kk = t >> 6, l = t & 63;
        const float2 p0 = partc[0][kk][l];
        const float2 p1 = partc[1][kk][l];
        float2 s;
        s.x = p0.x + p1.x;
        s.y = p0.y + p1.y;
        *(float2*)(out + ((size_t)(b * LK + k0 + kk)) * VD + l * 2) = s;
    }
}

extern "C" void kernel_launch(void* const* d_in, const int* in_sizes, int n_in,
                              void* d_out, int out_size, void* d_ws, size_t ws_size,
                              hipStream_t stream)
{
    const float* query = (const float*)d_in[0];
    const float* key   = (const float*)d_in[1];
    const float* value = (const float*)d_in[2];
    const float* Wq    = (const float*)d_in[3];
    const float* Wk    = (const float*)d_in[4];
    const float* v     = (const float*)d_in[5];
    float* out = (float*)d_out;

    float4* qe4 = (float4*)d_ws;                         // [B][32][256] float4
    float4* ke4 = qe4 + (size_t)B_ * 32 * 256;           // [B][256][32] float4

    proj_kernel<<<dim3(1024), 256, 0, stream>>>(query, key, Wq, Wk, qe4, ke4);
    attn_kernel<<<dim3(512), 1024, 0, stream>>>(qe4, ke4, v, value, out);
}

// Round 6
// 116.756 us; speedup vs baseline: 1.3184x; 1.3184x over previous
//
#include <hip/hip_runtime.h>

#define B_  16
#define LQ  256
#define LK  256
#define QD  256
#define HD  128
#define VD  128

// 2*log2(e): exp2(SCALE2*x) = e^{2x}
#define SCALE2 2.8853900817779268f
#define L2E    1.4426950408889634f
#define CTX_SIZE (B_ * LK * VD)

__device__ __forceinline__ float fast_exp2(float x) { return __builtin_amdgcn_exp2f(x); }
__device__ __forceinline__ float fast_rcp(float x)  { return __builtin_amdgcn_rcpf(x); }

// ---------------------------------------------------------------------------
// proj_kernel: 1024 blocks x 256 threads, XCD-affine: batch b -> XCD (b&7).
//   qe4[b][h4][q] = exp2(SCALE2*(query@Wq)) (float4 over 4 h, q-contig)
//   ke4[b][k][h4] = exp2(SCALE2*(key@Wk))   (row-major float4)
// ---------------------------------------------------------------------------
__global__ __launch_bounds__(256, 4) void proj_kernel(const float* __restrict__ query,
                                                      const float* __restrict__ key,
                                                      const float* __restrict__ Wq,
                                                      const float* __restrict__ Wk,
                                                      float4* __restrict__ qe4,
                                                      float4* __restrict__ ke4)
{
    __shared__ float  Xs[8][258];
    __shared__ float4 part[4][32][9];

    const int t = threadIdx.x;
    const int xcd = blockIdx.x & 7;
    const int i   = blockIdx.x >> 3;         // 0..127
    const bool isQ = (i < 64);
    const int j    = isQ ? i : (i - 64);     // 0..63
    const int b    = xcd + ((j >> 5) << 3);  // {xcd, xcd+8}
    const int rows0 = b * 256 + (j & 31) * 8;

    const float* X = isQ ? query : key;
    const float4* W4 = (const float4*)(isQ ? Wq : Wk);

    {
        const int r = t >> 5;
        const int c = (t & 31) * 8;
        const float4 x0 = *(const float4*)(X + (size_t)(rows0 + r) * QD + c);
        const float4 x1 = *(const float4*)(X + (size_t)(rows0 + r) * QD + c + 4);
        *(float4*)&Xs[r][c]     = x0;
        *(float4*)&Xs[r][c + 4] = x1;
    }
    __syncthreads();

    const int w    = t >> 6;
    const int lane = t & 63;
    const int hg   = lane & 31;
    const int mb   = lane >> 5;

    float4 acc[4];
#pragma unroll
    for (int m = 0; m < 4; m++) acc[m] = make_float4(0.f, 0.f, 0.f, 0.f);

    const int kbase = w * 64;
#pragma unroll 4
    for (int kk = 0; kk < 64; kk += 2) {
        const int k = kbase + kk;
        const float4 w0 = W4[(size_t)k * 32 + hg];
        const float4 w1 = W4[(size_t)(k + 1) * 32 + hg];
#pragma unroll
        for (int mi = 0; mi < 4; mi++) {
            const float2 x = *(const float2*)&Xs[mb + 2 * mi][k];
            acc[mi].x += x.x * w0.x + x.y * w1.x;
            acc[mi].y += x.x * w0.y + x.y * w1.y;
            acc[mi].z += x.x * w0.z + x.y * w1.z;
            acc[mi].w += x.x * w0.w + x.y * w1.w;
        }
    }
#pragma unroll
    for (int mi = 0; mi < 4; mi++) part[w][hg][mb + 2 * mi] = acc[mi];
    __syncthreads();

    if (isQ) {
        const int q8 = t & 7, h4 = t >> 3;
        float4 s = part[0][h4][q8];
        const float4 p1 = part[1][h4][q8];
        const float4 p2 = part[2][h4][q8];
        const float4 p3 = part[3][h4][q8];
        s.x += p1.x + p2.x + p3.x;  s.y += p1.y + p2.y + p3.y;
        s.z += p1.z + p2.z + p3.z;  s.w += p1.w + p2.w + p3.w;
        const float4 e = make_float4(fast_exp2(s.x * SCALE2), fast_exp2(s.y * SCALE2),
                                     fast_exp2(s.z * SCALE2), fast_exp2(s.w * SCALE2));
        const int row = rows0 + q8, bb = row >> 8, q = row & 255;
        qe4[((size_t)bb * 32 + h4) * 256 + q] = e;
    } else {
        const int h4 = t & 31, m = t >> 5;
        float4 s = part[0][h4][m];
        const float4 p1 = part[1][h4][m];
        const float4 p2 = part[2][h4][m];
        const float4 p3 = part[3][h4][m];
        s.x += p1.x + p2.x + p3.x;  s.y += p1.y + p2.y + p3.y;
        s.z += p1.z + p2.z + p3.z;  s.w += p1.w + p2.w + p3.w;
        const float4 e = make_float4(fast_exp2(s.x * SCALE2), fast_exp2(s.y * SCALE2),
                                     fast_exp2(s.z * SCALE2), fast_exp2(s.w * SCALE2));
        ke4[(size_t)(rows0 + m) * 32 + h4] = e;
    }
}

// ---------------------------------------------------------------------------
// score_kernel: 512 blocks x 1024 threads, XCD-affine (batch b -> XCD b&7).
// Block = (b, 8 k). Phase 1: thread=(q, kq) -> 2 k, loads interleaved (NO
// register batching: that spilled in R5). Phase 2: waves 0-7 softmax, k=w;
// write attention to out.
// ---------------------------------------------------------------------------
__global__ __launch_bounds__(1024, 8) void score_kernel(const float4* __restrict__ qe4,
                                                        const float4* __restrict__ ke4,
                                                        const float* __restrict__ v,
                                                        float* __restrict__ out)
{
    __shared__ float score_s[8][260];

    const int t   = threadIdx.x;
    const int xcd = blockIdx.x & 7;
    const int i   = blockIdx.x >> 3;        // 0..63
    const int b   = xcd + ((i >> 5) << 3);  // {xcd, xcd+8}
    const int k0  = (i & 31) << 3;

    const int kq = t >> 8;                  // 0..3 (wave-uniform)
    const int q  = t & 255;

    const float4* qb = qe4 + (size_t)b * 32 * 256;                 // [h4][q]
    const float4* kb = ke4 + ((size_t)b * LK + k0 + kq * 2) * 32;  // 2 rows
    const float4* v4 = (const float4*)v;

    float acc0 = 0.f, acc1 = 0.f;
#pragma unroll 4
    for (int h4 = 0; h4 < 32; h4++) {
        const float4 qv = qb[(size_t)h4 * 256 + q];
        const float4 vv = v4[h4];
        const float4 ka = kb[h4];
        const float4 kc = kb[32 + h4];
        acc0 += vv.x * fast_rcp(qv.x * ka.x + 1.f) + vv.y * fast_rcp(qv.y * ka.y + 1.f)
              + vv.z * fast_rcp(qv.z * ka.z + 1.f) + vv.w * fast_rcp(qv.w * ka.w + 1.f);
        acc1 += vv.x * fast_rcp(qv.x * kc.x + 1.f) + vv.y * fast_rcp(qv.y * kc.y + 1.f)
              + vv.z * fast_rcp(qv.z * kc.z + 1.f) + vv.w * fast_rcp(qv.w * kc.w + 1.f);
    }
    float sumv = 0.f;  // wave-uniform
#pragma unroll
    for (int h4 = 0; h4 < 32; h4++) {
        const float4 vv = v4[h4];
        sumv += vv.x + vv.y + vv.z + vv.w;
    }
    score_s[kq * 2 + 0][q] = sumv - 2.f * acc0;
    score_s[kq * 2 + 1][q] = sumv - 2.f * acc1;
    __syncthreads();

    if (t < 512) {
        const int w = t >> 6, lane = t & 63;
        float x0 = score_s[w][lane];
        float x1 = score_s[w][lane + 64];
        float x2 = score_s[w][lane + 128];
        float x3 = score_s[w][lane + 192];
        float m = fmaxf(fmaxf(x0, x1), fmaxf(x2, x3));
#pragma unroll
        for (int off = 32; off >= 1; off >>= 1) m = fmaxf(m, __shfl_xor(m, off));
        float e0 = fast_exp2((x0 - m) * L2E);
        float e1 = fast_exp2((x1 - m) * L2E);
        float e2 = fast_exp2((x2 - m) * L2E);
        float e3 = fast_exp2((x3 - m) * L2E);
        float s = e0 + e1 + e2 + e3;
#pragma unroll
        for (int off = 32; off >= 1; off >>= 1) s += __shfl_xor(s, off);
        const float rs = fast_rcp(s);
        float* ao = out + CTX_SIZE + ((size_t)(b * LK + k0 + w)) * LQ;
        ao[lane]       = e0 * rs;
        ao[lane + 64]  = e1 * rs;
        ao[lane + 128] = e2 * rs;
        ao[lane + 192] = e3 * rs;
    }
}

// ---------------------------------------------------------------------------
// ctx_kernel: 512 blocks x 256 threads, same XCD-affine (b,k0) mapping as
// score (attention rows are L2-local). context[k][vd] = sum_q A[k][q]*V[q][vd].
// Thread = (qsub = t>>5, vd4 = t&31): reads value exactly once per block
// (1x redundancy), A broadcast from LDS, acc[8] float4 register tile,
// LDS reduce over the 8 q-slices.
// ---------------------------------------------------------------------------
__global__ __launch_bounds__(256, 4) void ctx_kernel(const float* __restrict__ value,
                                                     float* __restrict__ out)
{
    __shared__ float  At[8][260];           // attention rows k0..k0+7
    __shared__ float4 part[8][8][32];       // [qsub][k][vd4]

    const int t   = threadIdx.x;
    const int xcd = blockIdx.x & 7;
    const int i   = blockIdx.x >> 3;        // 0..63
    const int b   = xcd + ((i >> 5) << 3);
    const int k0  = (i & 31) << 3;

    // ---- stage A (8 x 256 floats, coalesced float4) ----
    {
        const float* ab = out + CTX_SIZE + ((size_t)(b * LK + k0)) * LQ;
        const int r = t >> 5, c = (t & 31) * 4;
        *(float4*)&At[r][c]       = *(const float4*)(ab + (size_t)r * LQ + c);
        *(float4*)&At[r][c + 128] = *(const float4*)(ab + (size_t)r * LQ + c + 128);
    }
    __syncthreads();

    const int qsub = t >> 5;                // 0..7 -> q slice [qsub*32, +32)
    const int vd4  = t & 31;
    const float4* valb = (const float4*)(value + (size_t)b * LQ * VD);

    float4 acc[8];
#pragma unroll
    for (int k = 0; k < 8; k++) acc[k] = make_float4(0.f, 0.f, 0.f, 0.f);

#pragma unroll 4
    for (int iq = 0; iq < 32; iq++) {
        const int q = qsub * 32 + iq;
        const float4 vv = valb[(size_t)q * 32 + vd4];
#pragma unroll
        for (int k = 0; k < 8; k++) {
            const float a = At[k][q];       // 2-way broadcast across wave: free
            acc[k].x += a * vv.x;
            acc[k].y += a * vv.y;
            acc[k].z += a * vv.z;
            acc[k].w += a * vv.w;
        }
    }
#pragma unroll
    for (int k = 0; k < 8; k++) part[qsub][k][vd4] = acc[k];
    __syncthreads();

    // ---- reduce over qsub; thread = (k = t>>5, vd4 = t&31) ----
    {
        const int k = t >> 5, c = t & 31;
        float4 s = part[0][k][c];
#pragma unroll
        for (int qs = 1; qs < 8; qs++) {
            const float4 p = part[qs][k][c];
            s.x += p.x; s.y += p.y; s.z += p.z; s.w += p.w;
        }
        *(float4*)(out + ((size_t)(b * LK + k0 + k)) * VD + c * 4) = s;
    }
}

extern "C" void kernel_launch(void* const* d_in, const int* in_sizes, int n_in,
                              void* d_out, int out_size, void* d_ws, size_t ws_size,
                              hipStream_t stream)
{
    const float* query = (const float*)d_in[0];
    const float* key   = (const float*)d_in[1];
    const float* value = (const float*)d_in[2];
    const float* Wq    = (const float*)d_in[3];
    const float* Wk    = (const float*)d_in[4];
    const float* v     = (const float*)d_in[5];
    float* out = (float*)d_out;

    float4* qe4 = (float4*)d_ws;                         // [B][32][256] float4
    float4* ke4 = qe4 + (size_t)B_ * 32 * 256;           // [B][256][32] float4

    proj_kernel<<<dim3(1024), 256, 0, stream>>>(query, key, Wq, Wk, qe4, ke4);
    score_kernel<<<dim3(512), 1024, 0, stream>>>(qe4, ke4, v, out);
    ctx_kernel<<<dim3(512), 256, 0, stream>>>(value, out);
}

// Round 7
// 111.825 us; speedup vs baseline: 1.3766x; 1.0441x over previous
//
#include <hip/hip_runtime.h>

#define B_  16
#define LQ  256
#define LK  256
#define QD  256
#define HD  128
#define VD  128

// 2*log2(e): exp2(SCALE2*x) = e^{2x}
#define SCALE2 2.8853900817779268f
#define CTX_SIZE (B_ * LK * VD)

__device__ __forceinline__ float fast_exp2(float x) { return __builtin_amdgcn_exp2f(x); }
__device__ __forceinline__ float fast_rcp(float x)  { return __builtin_amdgcn_rcpf(x); }

// ---------------------------------------------------------------------------
// proj_kernel: 1024 blocks x 256 threads, XCD-affine: batch b -> XCD (b&7).
//   qe4[b][h4][q] = exp2(SCALE2*(query@Wq)) (float4 over 4 h, q-contig)
//   ke4[b][k][h4] = exp2(SCALE2*(key@Wk))   (row-major float4)
// ---------------------------------------------------------------------------
__global__ __launch_bounds__(256, 4) void proj_kernel(const float* __restrict__ query,
                                                      const float* __restrict__ key,
                                                      const float* __restrict__ Wq,
                                                      const float* __restrict__ Wk,
                                                      float4* __restrict__ qe4,
                                                      float4* __restrict__ ke4)
{
    __shared__ float  Xs[8][258];
    __shared__ float4 part[4][32][9];

    const int t = threadIdx.x;
    const int xcd = blockIdx.x & 7;
    const int i   = blockIdx.x >> 3;         // 0..127
    const bool isQ = (i < 64);
    const int j    = isQ ? i : (i - 64);     // 0..63
    const int b    = xcd + ((j >> 5) << 3);  // {xcd, xcd+8}
    const int rows0 = b * 256 + (j & 31) * 8;

    const float* X = isQ ? query : key;
    const float4* W4 = (const float4*)(isQ ? Wq : Wk);

    {
        const int r = t >> 5;
        const int c = (t & 31) * 8;
        const float4 x0 = *(const float4*)(X + (size_t)(rows0 + r) * QD + c);
        const float4 x1 = *(const float4*)(X + (size_t)(rows0 + r) * QD + c + 4);
        *(float4*)&Xs[r][c]     = x0;
        *(float4*)&Xs[r][c + 4] = x1;
    }
    __syncthreads();

    const int w    = t >> 6;
    const int lane = t & 63;
    const int hg   = lane & 31;
    const int mb   = lane >> 5;

    float4 acc[4];
#pragma unroll
    for (int m = 0; m < 4; m++) acc[m] = make_float4(0.f, 0.f, 0.f, 0.f);

    const int kbase = w * 64;
#pragma unroll 4
    for (int kk = 0; kk < 64; kk += 2) {
        const int k = kbase + kk;
        const float4 w0 = W4[(size_t)k * 32 + hg];
        const float4 w1 = W4[(size_t)(k + 1) * 32 + hg];
#pragma unroll
        for (int mi = 0; mi < 4; mi++) {
            const float2 x = *(const float2*)&Xs[mb + 2 * mi][k];
            acc[mi].x += x.x * w0.x + x.y * w1.x;
            acc[mi].y += x.x * w0.y + x.y * w1.y;
            acc[mi].z += x.x * w0.z + x.y * w1.z;
            acc[mi].w += x.x * w0.w + x.y * w1.w;
        }
    }
#pragma unroll
    for (int mi = 0; mi < 4; mi++) part[w][hg][mb + 2 * mi] = acc[mi];
    __syncthreads();

    if (isQ) {
        const int q8 = t & 7, h4 = t >> 3;
        float4 s = part[0][h4][q8];
        const float4 p1 = part[1][h4][q8];
        const float4 p2 = part[2][h4][q8];
        const float4 p3 = part[3][h4][q8];
        s.x += p1.x + p2.x + p3.x;  s.y += p1.y + p2.y + p3.y;
        s.z += p1.z + p2.z + p3.z;  s.w += p1.w + p2.w + p3.w;
        const float4 e = make_float4(fast_exp2(s.x * SCALE2), fast_exp2(s.y * SCALE2),
                                     fast_exp2(s.z * SCALE2), fast_exp2(s.w * SCALE2));
        const int row = rows0 + q8, bb = row >> 8, q = row & 255;
        qe4[((size_t)bb * 32 + h4) * 256 + q] = e;
    } else {
        const int h4 = t & 31, m = t >> 5;
        float4 s = part[0][h4][m];
        const float4 p1 = part[1][h4][m];
        const float4 p2 = part[2][h4][m];
        const float4 p3 = part[3][h4][m];
        s.x += p1.x + p2.x + p3.x;  s.y += p1.y + p2.y + p3.y;
        s.z += p1.z + p2.z + p3.z;  s.w += p1.w + p2.w + p3.w;
        const float4 e = make_float4(fast_exp2(s.x * SCALE2), fast_exp2(s.y * SCALE2),
                                     fast_exp2(s.z * SCALE2), fast_exp2(s.w * SCALE2));
        ke4[(size_t)(rows0 + m) * 32 + h4] = e;
    }
}

// ---------------------------------------------------------------------------
// score_kernel v2: ZERO barriers, zero LDS, fully wave-independent.
// 2048 blocks x 128 threads (2 waves). Wave = one (b, k): lane holds
// q = lane, lane+64, lane+128, lane+192. Softmax entirely in-wave.
// sumv cancels in softmax: p ~ exp2(-SCALE2*(acc - min_acc)).
// XCD-affine: batch b -> XCD (b&7).
// ---------------------------------------------------------------------------
__global__ __launch_bounds__(128, 8) void score_kernel(const float4* __restrict__ qe4,
                                                       const float4* __restrict__ ke4,
                                                       const float* __restrict__ v,
                                                       float* __restrict__ out)
{
    const int t    = threadIdx.x;
    const int wv   = t >> 6;                 // 0..1
    const int lane = t & 63;
    const int xcd  = blockIdx.x & 7;
    const int r    = blockIdx.x >> 3;        // 0..255
    const int b    = xcd + ((r & 1) << 3);   // {xcd, xcd+8}
    const int k    = (r >> 1) * 2 + wv;      // 0..255

    const float4* qb = qe4 + (size_t)b * 32 * 256;        // [h4][q]
    const float4* kb = ke4 + ((size_t)b * LK + k) * 32;   // this wave's k row
    const float4* v4 = (const float4*)v;

    float acc0 = 0.f, acc1 = 0.f, acc2 = 0.f, acc3 = 0.f;
#pragma unroll 2
    for (int h4 = 0; h4 < 32; h4++) {
        const float4 kv = kb[h4];            // wave-uniform, L1-resident
        const float4 vv = v4[h4];            // wave-uniform, L1-resident
        const float4 q0 = qb[(size_t)h4 * 256 + lane];
        const float4 q1 = qb[(size_t)h4 * 256 + lane + 64];
        const float4 q2 = qb[(size_t)h4 * 256 + lane + 128];
        const float4 q3 = qb[(size_t)h4 * 256 + lane + 192];
        acc0 += vv.x * fast_rcp(q0.x * kv.x + 1.f) + vv.y * fast_rcp(q0.y * kv.y + 1.f)
              + vv.z * fast_rcp(q0.z * kv.z + 1.f) + vv.w * fast_rcp(q0.w * kv.w + 1.f);
        acc1 += vv.x * fast_rcp(q1.x * kv.x + 1.f) + vv.y * fast_rcp(q1.y * kv.y + 1.f)
              + vv.z * fast_rcp(q1.z * kv.z + 1.f) + vv.w * fast_rcp(q1.w * kv.w + 1.f);
        acc2 += vv.x * fast_rcp(q2.x * kv.x + 1.f) + vv.y * fast_rcp(q2.y * kv.y + 1.f)
              + vv.z * fast_rcp(q2.z * kv.z + 1.f) + vv.w * fast_rcp(q2.w * kv.w + 1.f);
        acc3 += vv.x * fast_rcp(q3.x * kv.x + 1.f) + vv.y * fast_rcp(q3.y * kv.y + 1.f)
              + vv.z * fast_rcp(q3.z * kv.z + 1.f) + vv.w * fast_rcp(q3.w * kv.w + 1.f);
    }

    // score_q = sumv - 2*acc_q; softmax over q: sumv cancels, max -> min(acc).
    float amin = fminf(fminf(acc0, acc1), fminf(acc2, acc3));
#pragma unroll
    for (int off = 32; off >= 1; off >>= 1) amin = fminf(amin, __shfl_xor(amin, off));
    const float e0 = fast_exp2(-SCALE2 * (acc0 - amin));
    const float e1 = fast_exp2(-SCALE2 * (acc1 - amin));
    const float e2 = fast_exp2(-SCALE2 * (acc2 - amin));
    const float e3 = fast_exp2(-SCALE2 * (acc3 - amin));
    float s = e0 + e1 + e2 + e3;
#pragma unroll
    for (int off = 32; off >= 1; off >>= 1) s += __shfl_xor(s, off);
    const float rs = fast_rcp(s);

    float* ao = out + CTX_SIZE + ((size_t)(b * LK + k)) * LQ;
    ao[lane]       = e0 * rs;
    ao[lane + 64]  = e1 * rs;
    ao[lane + 128] = e2 * rs;
    ao[lane + 192] = e3 * rs;
}

// ---------------------------------------------------------------------------
// ctx_kernel: 512 blocks x 256 threads, XCD-affine (b,k0) mapping.
// context[k][vd] = sum_q A[k][q]*V[q][vd]; value read exactly once per block.
// ---------------------------------------------------------------------------
__global__ __launch_bounds__(256, 4) void ctx_kernel(const float* __restrict__ value,
                                                     float* __restrict__ out)
{
    __shared__ float  At[8][260];           // attention rows k0..k0+7
    __shared__ float4 part[8][8][32];       // [qsub][k][vd4]

    const int t   = threadIdx.x;
    const int xcd = blockIdx.x & 7;
    const int i   = blockIdx.x >> 3;        // 0..63
    const int b   = xcd + ((i >> 5) << 3);
    const int k0  = (i & 31) << 3;

    {
        const float* ab = out + CTX_SIZE + ((size_t)(b * LK + k0)) * LQ;
        const int r = t >> 5, c = (t & 31) * 4;
        *(float4*)&At[r][c]       = *(const float4*)(ab + (size_t)r * LQ + c);
        *(float4*)&At[r][c + 128] = *(const float4*)(ab + (size_t)r * LQ + c + 128);
    }
    __syncthreads();

    const int qsub = t >> 5;                // 0..7 -> q slice [qsub*32, +32)
    const int vd4  = t & 31;
    const float4* valb = (const float4*)(value + (size_t)b * LQ * VD);

    float4 acc[8];
#pragma unroll
    for (int k = 0; k < 8; k++) acc[k] = make_float4(0.f, 0.f, 0.f, 0.f);

#pragma unroll 4
    for (int iq = 0; iq < 32; iq++) {
        const int q = qsub * 32 + iq;
        const float4 vv = valb[(size_t)q * 32 + vd4];
#pragma unroll
        for (int k = 0; k < 8; k++) {
            const float a = At[k][q];
            acc[k].x += a * vv.x;
            acc[k].y += a * vv.y;
            acc[k].z += a * vv.z;
            acc[k].w += a * vv.w;
        }
    }
#pragma unroll
    for (int k = 0; k < 8; k++) part[qsub][k][vd4] = acc[k];
    __syncthreads();

    {
        const int k = t >> 5, c = t & 31;
        float4 s = part[0][k][c];
#pragma unroll
        for (int qs = 1; qs < 8; qs++) {
            const float4 p = part[qs][k][c];
            s.x += p.x; s.y += p.y; s.z += p.z; s.w += p.w;
        }
        *(float4*)(out + ((size_t)(b * LK + k0 + k)) * VD + c * 4) = s;
    }
}

extern "C" void kernel_launch(void* const* d_in, const int* in_sizes, int n_in,
                              void* d_out, int out_size, void* d_ws, size_t ws_size,
                              hipStream_t stream)
{
    const float* query = (const float*)d_in[0];
    const float* key   = (const float*)d_in[1];
    const float* value = (const float*)d_in[2];
    const float* Wq    = (const float*)d_in[3];
    const float* Wk    = (const float*)d_in[4];
    const float* v     = (const float*)d_in[5];
    float* out = (float*)d_out;

    float4* qe4 = (float4*)d_ws;                         // [B][32][256] float4
    float4* ke4 = qe4 + (size_t)B_ * 32 * 256;           // [B][256][32] float4

    proj_kernel<<<dim3(1024), 256, 0, stream>>>(query, key, Wq, Wk, qe4, ke4);
    score_kernel<<<dim3(2048), 128, 0, stream>>>(qe4, ke4, v, out);
    ctx_kernel<<<dim3(512), 256, 0, stream>>>(value, out);
}